// Round 4
// baseline (546.274 us; speedup 1.0000x reference)
//
#include <hip/hip_runtime.h>
#include <math.h>

#define HD __device__ __forceinline__

constexpr int TT = 2048;   // tokens = B*S
constexpr int HH = 1024;   // hidden
constexpr int II = 2816;   // intermediate
constexpr int EE = 8;      // experts
constexpr int NK1 = HH / 64;     // 16 k-tiles for gemm1
constexpr int NK2 = II / 64;     // 44 k-tiles for gemm2
constexpr int KS2 = 2;           // gemm2 k-split
constexpr int HALF2 = NK2 / KS2; // 22
constexpr int MAXTILES = 40;
constexpr size_t EW = (size_t)EE * HH * II;   // elements per weight tensor

typedef short  bf16x8  __attribute__((ext_vector_type(8)));
typedef float  floatx4 __attribute__((ext_vector_type(4)));

// ---- workspace layout (bytes) ----
constexpr size_t OFF_XB    = 0;                                // [TT][HH] bf16
constexpr size_t OFF_WG    = OFF_XB    + (size_t)TT*HH*2;      // bf16 natural [E][H][I]
constexpr size_t OFF_WU    = OFF_WG    + EW*2;
constexpr size_t OFF_WD    = OFF_WU    + EW*2;                 // bf16 natural [E][I][H]
constexpr size_t OFF_ABUF  = OFF_WD    + EW*2;                 // [2T][I] bf16
constexpr size_t OFF_CNT   = OFF_ABUF  + (size_t)2*TT*II*2;
constexpr size_t OFF_OFFS  = OFF_CNT   + 256;
constexpr size_t OFF_MDESC = OFF_OFFS  + 256;
constexpr size_t OFF_EMETA = OFF_MDESC + 256;                  // [T][2] int
constexpr size_t OFF_WMETA = OFF_EMETA + 16384;                // [T][2] float
constexpr size_t OFF_TLIST = OFF_WMETA + 16384;                // [2T] int
constexpr size_t OFF_GWL   = OFF_TLIST + 16384;                // [2T] float

HD unsigned short f2bf(float f) {
  union { float f; unsigned int u; } v; v.f = f;
  return (unsigned short)((v.u + 0x7fffu + ((v.u >> 16) & 1u)) >> 16);
}

HD void load_lds16(const void* gptr, void* lptr) {
  __builtin_amdgcn_global_load_lds(
      (const __attribute__((address_space(1))) void*)gptr,
      (__attribute__((address_space(3))) void*)lptr,
      16, 0, 0);
}

// load 8 bf16x8 rows (8 k-rows x 8 n-cols) from natural [k][n] bf16 weights
HD void load_w8b(bf16x8* wv, const unsigned short* wsrc, int k0, int kg, int stride) {
#pragma unroll
  for (int j = 0; j < 8; ++j)
    wv[j] = *(const bf16x8*)&wsrc[(size_t)(k0 + kg * 8 + j) * stride];
}

// 8x8 register transpose -> 8 ds_write_b128 into swizzled [n][k] LDS tile.
// lane = ng*8+kg: 8-lane phase groups have kg 0..7 -> chunk kg^nn spans all
// 8 bank groups -> conflict-free (round-3 lesson: wng-in-low-bits was 4-way).
HD void store_w8t(const bf16x8* wv, unsigned short* ldsT, int ng, int kg) {
#pragma unroll
  for (int nn = 0; nn < 8; ++nn) {
    bf16x8 o;
#pragma unroll
    for (int j = 0; j < 8; ++j) o[j] = wv[j][nn];
    *(bf16x8*)&ldsT[(ng * 8 + nn) * 64 + ((kg ^ nn) * 8)] = o;
  }
}

// ---------------- prep: zero out + counts, convert x -> bf16 ----------------
__global__ __launch_bounds__(256)
void prep_kernel(const float* __restrict__ x, unsigned short* __restrict__ xb,
                 float* __restrict__ out, int* __restrict__ counts) {
  const int i = blockIdx.x * blockDim.x + threadIdx.x;   // 0 .. TT*HH/4-1
  if (i < EE) counts[i] = 0;
  const float4 z = {0.f, 0.f, 0.f, 0.f};
  ((float4*)out)[i] = z;
  float4 v = ((const float4*)x)[i];
  ushort4 o;
  o.x = f2bf(v.x); o.y = f2bf(v.y); o.z = f2bf(v.z); o.w = f2bf(v.w);
  ((ushort4*)xb)[i] = o;
}

// ---------------- streaming cast: 3 weight tensors fp32 -> bf16 (natural layout) ----------------
__global__ __launch_bounds__(256)
void cast3_kernel(const float* __restrict__ wg, const float* __restrict__ wu,
                  const float* __restrict__ wd,
                  unsigned short* __restrict__ gb, unsigned short* __restrict__ ub,
                  unsigned short* __restrict__ db) {
  const int i = blockIdx.x * blockDim.x + threadIdx.x;   // 0 .. EW/4-1
  const float* src; unsigned short* dst;
  if (blockIdx.y == 0)      { src = wg; dst = gb; }
  else if (blockIdx.y == 1) { src = wu; dst = ub; }
  else                      { src = wd; dst = db; }
  float4 v = ((const float4*)src)[i];
  ushort4 o;
  o.x = f2bf(v.x); o.y = f2bf(v.y); o.z = f2bf(v.z); o.w = f2bf(v.w);
  ((ushort4*)dst)[i] = o;
}

// ---------------- router (fp32, exact top-k semantics) ----------------
__global__ __launch_bounds__(64)
void router_kernel(const float* __restrict__ x, const float* __restrict__ w_router,
                   int* __restrict__ counts, int* __restrict__ emeta, float* __restrict__ wmeta) {
  const int t = blockIdx.x;
  const int lane = threadIdx.x;
  float acc[EE];
#pragma unroll
  for (int e = 0; e < EE; ++e) acc[e] = 0.f;
  for (int h = lane; h < HH; h += 64) {
    const float xv = x[(size_t)t * HH + h];
    const float* wr = w_router + (size_t)h * EE;
#pragma unroll
    for (int e = 0; e < EE; ++e) acc[e] += xv * wr[e];
  }
#pragma unroll
  for (int e = 0; e < EE; ++e) {
#pragma unroll
    for (int off = 32; off > 0; off >>= 1) acc[e] += __shfl_xor(acc[e], off, 64);
  }
  if (lane == 0) {
    int e0 = 0; float v0 = acc[0];
#pragma unroll
    for (int e = 1; e < EE; ++e) if (acc[e] > v0) { v0 = acc[e]; e0 = e; }
    int e1 = -1; float v1 = -3.4e38f;
#pragma unroll
    for (int e = 0; e < EE; ++e) if (e != e0 && acc[e] > v1) { v1 = acc[e]; e1 = e; }
    const float ex = __expf(v1 - v0);
    const float s  = 1.f + ex;
    emeta[2 * t] = e0; emeta[2 * t + 1] = e1;
    wmeta[2 * t] = 1.f / s; wmeta[2 * t + 1] = ex / s;
    atomicAdd(&counts[e0], 1);
    atomicAdd(&counts[e1], 1);
  }
}

// ---------------- scan + fill + mdesc: ONE block ----------------
__global__ __launch_bounds__(256)
void scanfill_kernel(const int* __restrict__ counts, const int* __restrict__ emeta,
                     const float* __restrict__ wmeta,
                     int* __restrict__ offsets, int* __restrict__ mdesc,
                     int* __restrict__ token_list, float* __restrict__ gw_list) {
  __shared__ int s_off[EE];
  __shared__ int s_fill[EE];
  const int tid = threadIdx.x;
  if (tid < EE) s_fill[tid] = 0;
  if (tid == 0) {
    int s = 0;
    int nt = 0;
    for (int e = 0; e < EE; ++e) {
      const int c = counts[e];
      s_off[e] = s; offsets[e] = s;
      for (int m = 0; m < c; m += 128) mdesc[1 + nt++] = (e << 20) | m;
      s += c;
    }
    offsets[EE] = s;
    mdesc[0] = nt;
  }
  __syncthreads();
  for (int t = tid; t < TT; t += 256) {
#pragma unroll
    for (int s = 0; s < 2; ++s) {
      const int e = emeta[2 * t + s];
      const int pos = atomicAdd(&s_fill[e], 1);
      token_list[s_off[e] + pos] = t;
      gw_list[s_off[e] + pos] = wmeta[2 * t + s];
    }
  }
}

// ---------------- GEMM1: A = silu(X Wg) * (X Wu); fused bf16 weight transpose ----------------
__global__ __launch_bounds__(256, 3)
void gemm1_kernel(const unsigned short* __restrict__ xb,
                  const unsigned short* __restrict__ wg,   // [E][H][I] bf16 natural
                  const unsigned short* __restrict__ wu,
                  const int* __restrict__ offsets,
                  const int* __restrict__ mdesc,
                  const int* __restrict__ token_list,
                  unsigned short* __restrict__ Abuf) {
  if ((int)blockIdx.y >= mdesc[0]) return;
  const int d = mdesc[1 + blockIdx.y];
  const int e = d >> 20;
  const int m_base = d & 0xFFFFF;
  const int off_e = offsets[e];
  const int n_e = offsets[e + 1] - off_e;
  const int n_base = blockIdx.x * 64;   // I dimension

  __shared__ __attribute__((aligned(16))) unsigned short ldsA[128 * 64];
  __shared__ __attribute__((aligned(16))) unsigned short ldsG[64 * 64];
  __shared__ __attribute__((aligned(16))) unsigned short ldsU[64 * 64];

  const int tid = threadIdx.x;
  const int wave = tid >> 6;
  const int lane = tid & 63;
  const int quad = lane >> 4;
  const int l16 = lane & 15;
  const int wave_m = (wave & 1) * 64;
  const int wave_n = (wave >> 1) * 32;

  const int srow = lane >> 3;               // 0..7
  const int clog = (lane & 7) ^ srow;       // xor-swizzled 16B chunk

  // A-staging pointers (gathered token rows)
  const unsigned short* gA[4];
#pragma unroll
  for (int it = 0; it < 4; ++it) {
    const int r = it * 32 + wave * 8 + srow;
    int ar = m_base + r; if (ar > n_e - 1) ar = n_e - 1;
    const int tok = token_list[off_e + ar];
    gA[it] = xb + (size_t)tok * HH + clog * 8;
  }

  // weight staging: threads 0..63 -> G, 64..127 -> U; thread = (kg low, ng high)
  const int t6 = tid & 63;
  const int kg = t6 & 7;
  const int ng = t6 >> 3;
  const unsigned short* wsrc =
      (tid < 64 ? wg : wu) + (size_t)e * HH * II + (size_t)(n_base + ng * 8);
  unsigned short* ldsT = (tid < 64 ? ldsG : ldsU);

  floatx4 accG[4][2], accU[4][2];
  const floatx4 fz = {0.f, 0.f, 0.f, 0.f};
#pragma unroll
  for (int i = 0; i < 4; ++i)
#pragma unroll
    for (int j = 0; j < 2; ++j) { accG[i][j] = fz; accU[i][j] = fz; }

  bf16x8 wv[8];
  if (tid < 128) load_w8b(wv, wsrc, 0, kg, II);

  for (int kt = 0; kt < NK1; ++kt) {
    const int k0 = kt * 64;
#pragma unroll
    for (int it = 0; it < 4; ++it)
      load_lds16(gA[it] + k0, &ldsA[(it * 32 + wave * 8) * 64]);
    if (tid < 128) {
      store_w8t(wv, ldsT, ng, kg);
      const int ktn = (kt + 1 < NK1) ? kt + 1 : kt;
      load_w8b(wv, wsrc, ktn * 64, kg, II);   // prefetch next, lands during MFMA
    }
    __syncthreads();
#pragma unroll
    for (int ks = 0; ks < 2; ++ks) {
      bf16x8 af[4], bg[2], bu[2];
#pragma unroll
      for (int f = 0; f < 4; ++f) {
        const int rowA = wave_m + f * 16 + l16;
        const int cA = (ks * 4 + quad) ^ (rowA & 7);
        af[f] = *(const bf16x8*)&ldsA[rowA * 64 + cA * 8];
      }
#pragma unroll
      for (int f = 0; f < 2; ++f) {
        const int rowB = wave_n + f * 16 + l16;
        const int cB = (ks * 4 + quad) ^ (rowB & 7);
        bg[f] = *(const bf16x8*)&ldsG[rowB * 64 + cB * 8];
        bu[f] = *(const bf16x8*)&ldsU[rowB * 64 + cB * 8];
      }
#pragma unroll
      for (int mf = 0; mf < 4; ++mf)
#pragma unroll
        for (int nf = 0; nf < 2; ++nf) {
          accG[mf][nf] = __builtin_amdgcn_mfma_f32_16x16x32_bf16(af[mf], bg[nf], accG[mf][nf], 0, 0, 0);
          accU[mf][nf] = __builtin_amdgcn_mfma_f32_16x16x32_bf16(af[mf], bu[nf], accU[mf][nf], 0, 0, 0);
        }
    }
    __syncthreads();
  }

#pragma unroll
  for (int mf = 0; mf < 4; ++mf)
#pragma unroll
    for (int nf = 0; nf < 2; ++nf) {
      const int col = n_base + wave_n + nf * 16 + l16;
#pragma unroll
      for (int j = 0; j < 4; ++j) {
        const int r = m_base + wave_m + mf * 16 + quad * 4 + j;
        if (r < n_e) {
          const float g = accG[mf][nf][j];
          const float u = accU[mf][nf][j];
          const float a = (g / (1.f + __expf(-g))) * u;
          Abuf[(size_t)(off_e + r) * II + col] = f2bf(a);
        }
      }
    }
}

// ---------------- GEMM2: Y = A Wd; fused bf16 weight transpose; k-split x2 ----------------
__global__ __launch_bounds__(256, 3)
void gemm2_kernel(const unsigned short* __restrict__ Abuf,
                  const unsigned short* __restrict__ wd,   // [E][I][H] bf16 natural
                  const float* __restrict__ b_down,        // [E][H] fp32
                  const int* __restrict__ offsets,
                  const int* __restrict__ mdesc,
                  const int* __restrict__ token_list,
                  const float* __restrict__ gw_list,
                  float* __restrict__ out) {
  if ((int)blockIdx.y >= mdesc[0]) return;
  const int d = mdesc[1 + blockIdx.y];
  const int e = d >> 20;
  const int m_base = d & 0xFFFFF;
  const int off_e = offsets[e];
  const int n_e = offsets[e + 1] - off_e;
  const int n_base = blockIdx.x * 64;   // H dimension
  const int split = blockIdx.z;
  const int kt_lo = split * HALF2;
  const int kt_hi = kt_lo + HALF2;

  __shared__ __attribute__((aligned(16))) unsigned short ldsA[128 * 64];
  __shared__ __attribute__((aligned(16))) unsigned short ldsB[64 * 64];

  const int tid = threadIdx.x;
  const int wave = tid >> 6;
  const int lane = tid & 63;
  const int quad = lane >> 4;
  const int l16 = lane & 15;
  const int wave_m = (wave & 1) * 64;
  const int wave_n = (wave >> 1) * 32;

  const int srow = lane >> 3;
  const int clog = (lane & 7) ^ srow;

  const unsigned short* gA[4];
#pragma unroll
  for (int it = 0; it < 4; ++it) {
    const int r = it * 32 + wave * 8 + srow;
    int ar = m_base + r; if (ar > n_e - 1) ar = n_e - 1;
    gA[it] = Abuf + (size_t)(off_e + ar) * II + clog * 8;
  }

  const int kg = tid & 7;
  const int ng = (tid >> 3) & 7;
  const unsigned short* wsrc = wd + (size_t)e * II * HH + (size_t)(n_base + ng * 8);

  floatx4 acc[4][2];
  const floatx4 fz = {0.f, 0.f, 0.f, 0.f};
#pragma unroll
  for (int i = 0; i < 4; ++i)
#pragma unroll
    for (int j = 0; j < 2; ++j) acc[i][j] = fz;

  bf16x8 wv[8];
  if (tid < 64) load_w8b(wv, wsrc, kt_lo * 64, kg, HH);

  for (int kt = kt_lo; kt < kt_hi; ++kt) {
    const int k0 = kt * 64;
#pragma unroll
    for (int it = 0; it < 4; ++it)
      load_lds16(gA[it] + k0, &ldsA[(it * 32 + wave * 8) * 64]);
    if (tid < 64) {
      store_w8t(wv, ldsB, ng, kg);
      const int ktn = (kt + 1 < kt_hi) ? kt + 1 : kt;
      load_w8b(wv, wsrc, ktn * 64, kg, HH);
    }
    __syncthreads();
#pragma unroll
    for (int ks = 0; ks < 2; ++ks) {
      bf16x8 af[4], bf[2];
#pragma unroll
      for (int f = 0; f < 4; ++f) {
        const int rowA = wave_m + f * 16 + l16;
        const int cA = (ks * 4 + quad) ^ (rowA & 7);
        af[f] = *(const bf16x8*)&ldsA[rowA * 64 + cA * 8];
      }
#pragma unroll
      for (int f = 0; f < 2; ++f) {
        const int rowB = wave_n + f * 16 + l16;
        const int cB = (ks * 4 + quad) ^ (rowB & 7);
        bf[f] = *(const bf16x8*)&ldsB[rowB * 64 + cB * 8];
      }
#pragma unroll
      for (int mf = 0; mf < 4; ++mf)
#pragma unroll
        for (int nf = 0; nf < 2; ++nf)
          acc[mf][nf] = __builtin_amdgcn_mfma_f32_16x16x32_bf16(af[mf], bf[nf], acc[mf][nf], 0, 0, 0);
    }
    __syncthreads();
  }

#pragma unroll
  for (int mf = 0; mf < 4; ++mf)
#pragma unroll
    for (int nf = 0; nf < 2; ++nf) {
      const int col = n_base + wave_n + nf * 16 + l16;
      const float bd = (split == 0) ? b_down[e * HH + col] : 0.f;
#pragma unroll
      for (int j = 0; j < 4; ++j) {
        const int r = m_base + wave_m + mf * 16 + quad * 4 + j;
        if (r < n_e) {
          const int cr = off_e + r;
          const int tok = token_list[cr];
          const float gw = gw_list[cr];
          atomicAdd(&out[(size_t)tok * HH + col], gw * (acc[mf][nf][j] + bd));
        }
      }
    }
}

// ---------------- launch ----------------
extern "C" void kernel_launch(void* const* d_in, const int* in_sizes, int n_in,
                              void* d_out, int out_size, void* d_ws, size_t ws_size,
                              hipStream_t stream) {
  const float* x        = (const float*)d_in[0];
  const float* w_router = (const float*)d_in[1];
  const float* w_gate   = (const float*)d_in[2];
  const float* w_up     = (const float*)d_in[3];
  const float* w_down   = (const float*)d_in[4];
  const float* b_down   = (const float*)d_in[5];
  float* out = (float*)d_out;

  char* ws = (char*)d_ws;
  unsigned short* xb   = (unsigned short*)(ws + OFF_XB);
  unsigned short* wgb  = (unsigned short*)(ws + OFF_WG);
  unsigned short* wub  = (unsigned short*)(ws + OFF_WU);
  unsigned short* wdb  = (unsigned short*)(ws + OFF_WD);
  unsigned short* Abuf = (unsigned short*)(ws + OFF_ABUF);
  int*   counts  = (int*)(ws + OFF_CNT);
  int*   offsets = (int*)(ws + OFF_OFFS);
  int*   mdesc   = (int*)(ws + OFF_MDESC);
  int*   emeta   = (int*)(ws + OFF_EMETA);
  float* wmeta   = (float*)(ws + OFF_WMETA);
  int*   tlist   = (int*)(ws + OFF_TLIST);
  float* gwl     = (float*)(ws + OFF_GWL);

  prep_kernel<<<TT * HH / 4 / 256, 256, 0, stream>>>(x, xb, out, counts);
  router_kernel<<<TT, 64, 0, stream>>>(x, w_router, counts, emeta, wmeta);
  scanfill_kernel<<<1, 256, 0, stream>>>(counts, emeta, wmeta, offsets, mdesc, tlist, gwl);
  cast3_kernel<<<dim3((int)(EW / 4 / 256), 3), 256, 0, stream>>>(w_gate, w_up, w_down, wgb, wub, wdb);
  gemm1_kernel<<<dim3(II / 64, MAXTILES), 256, 0, stream>>>(xb, wgb, wub, offsets, mdesc, tlist, Abuf);
  gemm2_kernel<<<dim3(HH / 64, MAXTILES, KS2), 256, 0, stream>>>(Abuf, wdb, b_down, offsets, mdesc, tlist, gwl, out);
}

// Round 5
// 480.066 us; speedup vs baseline: 1.1379x; 1.1379x over previous
//
#include <hip/hip_runtime.h>
#include <math.h>

#define HD __device__ __forceinline__

constexpr int TT = 2048;   // tokens = B*S
constexpr int HH = 1024;   // hidden
constexpr int II = 2816;   // intermediate
constexpr int EE = 8;      // experts
constexpr int NK1 = HH / 64;     // 16 k-tiles gemm1
constexpr int NK2 = II / 64;     // 44 k-tiles gemm2
constexpr int KS2 = 2;           // gemm2 k-split
constexpr int HALF2 = NK2 / KS2; // 22
constexpr int MAXTILES = 40;

typedef short  bf16x8  __attribute__((ext_vector_type(8)));
typedef float  floatx4 __attribute__((ext_vector_type(4)));

// ---- workspace layout (bytes) ----
constexpr size_t OFF_XB    = 0;                                // [TT][HH] bf16
constexpr size_t OFF_WGT   = OFF_XB    + (size_t)TT*HH*2;      // wg^T bf16 [E][I][H]
constexpr size_t OFF_WUT   = OFF_WGT   + (size_t)EE*II*HH*2;   // wu^T bf16 [E][I][H]
constexpr size_t OFF_WDT   = OFF_WUT   + (size_t)EE*II*HH*2;   // wd^T bf16 [E][H][I]
constexpr size_t OFF_ABUF  = OFF_WDT   + (size_t)EE*HH*II*2;   // [2T][I] bf16
constexpr size_t OFF_CNT   = OFF_ABUF  + (size_t)2*TT*II*2;
constexpr size_t OFF_OFFS  = OFF_CNT   + 256;
constexpr size_t OFF_MDESC = OFF_OFFS  + 256;
constexpr size_t OFF_EMETA = OFF_MDESC + 256;                  // [T][2] int
constexpr size_t OFF_WMETA = OFF_EMETA + 16384;                // [T][2] float
constexpr size_t OFF_TLIST = OFF_WMETA + 16384;                // [2T] int
constexpr size_t OFF_GWL   = OFF_TLIST + 16384;                // [2T] float

HD unsigned short f2bf(float f) {
  union { float f; unsigned int u; } v; v.f = f;
  return (unsigned short)((v.u + 0x7fffu + ((v.u >> 16) & 1u)) >> 16);
}

HD void load_lds16(const void* gptr, void* lptr) {
  __builtin_amdgcn_global_load_lds(
      (const __attribute__((address_space(1))) void*)gptr,
      (__attribute__((address_space(3))) void*)lptr,
      16, 0, 0);
}

// ---------------- prep: zero out + counts, convert x -> bf16 ----------------
__global__ __launch_bounds__(256)
void prep_kernel(const float* __restrict__ x, unsigned short* __restrict__ xb,
                 float* __restrict__ out, int* __restrict__ counts) {
  const int i = blockIdx.x * blockDim.x + threadIdx.x;   // 0 .. TT*HH/4-1
  if (i < EE) counts[i] = 0;
  const float4 z = {0.f, 0.f, 0.f, 0.f};
  ((float4*)out)[i] = z;
  float4 v = ((const float4*)x)[i];
  ushort4 o;
  o.x = f2bf(v.x); o.y = f2bf(v.y); o.z = f2bf(v.z); o.w = f2bf(v.w);
  ((ushort4*)xb)[i] = o;
}

// ---------------- merged transpose+cast: all 3 tensors, all experts ----------------
// z = e*3 + t. t=0: wg [HH][II]->wgt [II][HH]; t=1: wu; t=2: wd [II][HH]->wdt [HH][II].
// grid (44, 16, 24); for t<2 x indexes C-tiles (44), y R-tiles (16); t=2 swapped.
__global__ __launch_bounds__(256)
void transpose_cast_kernel(const float* __restrict__ wg, const float* __restrict__ wu,
                           const float* __restrict__ wd,
                           unsigned short* __restrict__ wgt, unsigned short* __restrict__ wut,
                           unsigned short* __restrict__ wdt) {
  const int e = blockIdx.z / 3;
  const int t = blockIdx.z % 3;
  const float* src; unsigned short* dst; int R, C, r0, c0;
  if (t == 0)      { src = wg; dst = wgt; R = HH; C = II; c0 = blockIdx.x * 64; r0 = blockIdx.y * 64; }
  else if (t == 1) { src = wu; dst = wut; R = HH; C = II; c0 = blockIdx.x * 64; r0 = blockIdx.y * 64; }
  else             { src = wd; dst = wdt; R = II; C = HH; r0 = blockIdx.x * 64; c0 = blockIdx.y * 64; }
  const size_t base = (size_t)e * R * C;

  __shared__ float tile[64][65];
  const int sub = threadIdx.x >> 4;    // 0..15
  const int q   = threadIdx.x & 15;    // 0..15
#pragma unroll
  for (int it = 0; it < 4; ++it) {
    const int r = it * 16 + sub;
    const float4 v = *(const float4*)&src[base + (size_t)(r0 + r) * C + c0 + q * 4];
    tile[r][q * 4 + 0] = v.x; tile[r][q * 4 + 1] = v.y;
    tile[r][q * 4 + 2] = v.z; tile[r][q * 4 + 3] = v.w;
  }
  __syncthreads();
#pragma unroll
  for (int it = 0; it < 4; ++it) {
    const int c = it * 16 + sub;
    ushort4 o;
    o.x = f2bf(tile[q * 4 + 0][c]); o.y = f2bf(tile[q * 4 + 1][c]);
    o.z = f2bf(tile[q * 4 + 2][c]); o.w = f2bf(tile[q * 4 + 3][c]);
    *(ushort4*)&dst[base + (size_t)(c0 + c) * R + r0 + q * 4] = o;
  }
}

// ---------------- router (fp32, exact top-k semantics) ----------------
__global__ __launch_bounds__(64)
void router_kernel(const float* __restrict__ x, const float* __restrict__ w_router,
                   int* __restrict__ counts, int* __restrict__ emeta, float* __restrict__ wmeta) {
  const int t = blockIdx.x;
  const int lane = threadIdx.x;
  float acc[EE];
#pragma unroll
  for (int e = 0; e < EE; ++e) acc[e] = 0.f;
  for (int h = lane; h < HH; h += 64) {
    const float xv = x[(size_t)t * HH + h];
    const float* wr = w_router + (size_t)h * EE;
#pragma unroll
    for (int e = 0; e < EE; ++e) acc[e] += xv * wr[e];
  }
#pragma unroll
  for (int e = 0; e < EE; ++e) {
#pragma unroll
    for (int off = 32; off > 0; off >>= 1) acc[e] += __shfl_xor(acc[e], off, 64);
  }
  if (lane == 0) {
    int e0 = 0; float v0 = acc[0];
#pragma unroll
    for (int e = 1; e < EE; ++e) if (acc[e] > v0) { v0 = acc[e]; e0 = e; }
    int e1 = -1; float v1 = -3.4e38f;
#pragma unroll
    for (int e = 0; e < EE; ++e) if (e != e0 && acc[e] > v1) { v1 = acc[e]; e1 = e; }
    const float ex = __expf(v1 - v0);
    const float s  = 1.f + ex;
    emeta[2 * t] = e0; emeta[2 * t + 1] = e1;
    wmeta[2 * t] = 1.f / s; wmeta[2 * t + 1] = ex / s;
    atomicAdd(&counts[e0], 1);
    atomicAdd(&counts[e1], 1);
  }
}

// ---------------- scan + fill + mdesc: ONE block ----------------
__global__ __launch_bounds__(256)
void scanfill_kernel(const int* __restrict__ counts, const int* __restrict__ emeta,
                     const float* __restrict__ wmeta,
                     int* __restrict__ offsets, int* __restrict__ mdesc,
                     int* __restrict__ token_list, float* __restrict__ gw_list) {
  __shared__ int s_off[EE];
  __shared__ int s_fill[EE];
  const int tid = threadIdx.x;
  if (tid < EE) s_fill[tid] = 0;
  if (tid == 0) {
    int s = 0;
    int nt = 0;
    for (int e = 0; e < EE; ++e) {
      const int c = counts[e];
      s_off[e] = s; offsets[e] = s;
      for (int m = 0; m < c; m += 128) mdesc[1 + nt++] = (e << 20) | m;
      s += c;
    }
    offsets[EE] = s;
    mdesc[0] = nt;
  }
  __syncthreads();
  for (int t = tid; t < TT; t += 256) {
#pragma unroll
    for (int s = 0; s < 2; ++s) {
      const int e = emeta[2 * t + s];
      const int pos = atomicAdd(&s_fill[e], 1);
      token_list[s_off[e] + pos] = t;
      gw_list[s_off[e] + pos] = wmeta[2 * t + s];
    }
  }
}

// ---------------- GEMM1: A = silu(X Wg) * (X Wu); 128x64 tile, dual acc ----------------
// (round-2 verified structure: all staging via async global_load_lds, 0 conflicts)
__global__ __launch_bounds__(256, 4)
void gemm1_kernel(const unsigned short* __restrict__ xb,
                  const unsigned short* __restrict__ wgt,
                  const unsigned short* __restrict__ wut,
                  const int* __restrict__ offsets,
                  const int* __restrict__ mdesc,
                  const int* __restrict__ token_list,
                  unsigned short* __restrict__ Abuf) {
  if ((int)blockIdx.y >= mdesc[0]) return;
  const int d = mdesc[1 + blockIdx.y];
  const int e = d >> 20;
  const int m_base = d & 0xFFFFF;
  const int off_e = offsets[e];
  const int n_e = offsets[e + 1] - off_e;
  const int n_base = blockIdx.x * 64;   // I dimension

  __shared__ __attribute__((aligned(16))) unsigned short ldsA[128 * 64];
  __shared__ __attribute__((aligned(16))) unsigned short ldsG[64 * 64];
  __shared__ __attribute__((aligned(16))) unsigned short ldsU[64 * 64];

  const int tid = threadIdx.x;
  const int wave = tid >> 6;
  const int lane = tid & 63;
  const int quad = lane >> 4;
  const int l16 = lane & 15;
  const int wave_m = (wave & 1) * 64;
  const int wave_n = (wave >> 1) * 32;

  const int srow = lane >> 3;               // 0..7
  const int clog = (lane & 7) ^ srow;       // xor-swizzled 16B chunk

  const unsigned short* gA[4];
  const unsigned short* gG[2];
  const unsigned short* gU[2];
#pragma unroll
  for (int it = 0; it < 4; ++it) {
    const int r = it * 32 + wave * 8 + srow;
    int ar = m_base + r; if (ar > n_e - 1) ar = n_e - 1;
    const int tok = token_list[off_e + ar];
    gA[it] = xb + (size_t)tok * HH + clog * 8;
  }
#pragma unroll
  for (int it = 0; it < 2; ++it) {
    const int r = it * 32 + wave * 8 + srow;
    gG[it] = wgt + ((size_t)e * II + (n_base + r)) * HH + clog * 8;
    gU[it] = wut + ((size_t)e * II + (n_base + r)) * HH + clog * 8;
  }

  floatx4 accG[4][2], accU[4][2];
  const floatx4 fz = {0.f, 0.f, 0.f, 0.f};
#pragma unroll
  for (int i = 0; i < 4; ++i)
#pragma unroll
    for (int j = 0; j < 2; ++j) { accG[i][j] = fz; accU[i][j] = fz; }

  for (int kt = 0; kt < NK1; ++kt) {
    const int k0 = kt * 64;
#pragma unroll
    for (int it = 0; it < 4; ++it)
      load_lds16(gA[it] + k0, &ldsA[(it * 32 + wave * 8) * 64]);
#pragma unroll
    for (int it = 0; it < 2; ++it) {
      load_lds16(gG[it] + k0, &ldsG[(it * 32 + wave * 8) * 64]);
      load_lds16(gU[it] + k0, &ldsU[(it * 32 + wave * 8) * 64]);
    }
    __syncthreads();
#pragma unroll
    for (int ks = 0; ks < 2; ++ks) {
      bf16x8 af[4], bg[2], bu[2];
#pragma unroll
      for (int f = 0; f < 4; ++f) {
        const int rowA = wave_m + f * 16 + l16;
        const int cA = (ks * 4 + quad) ^ (rowA & 7);
        af[f] = *(const bf16x8*)&ldsA[rowA * 64 + cA * 8];
      }
#pragma unroll
      for (int f = 0; f < 2; ++f) {
        const int rowB = wave_n + f * 16 + l16;
        const int cB = (ks * 4 + quad) ^ (rowB & 7);
        bg[f] = *(const bf16x8*)&ldsG[rowB * 64 + cB * 8];
        bu[f] = *(const bf16x8*)&ldsU[rowB * 64 + cB * 8];
      }
#pragma unroll
      for (int mf = 0; mf < 4; ++mf)
#pragma unroll
        for (int nf = 0; nf < 2; ++nf) {
          accG[mf][nf] = __builtin_amdgcn_mfma_f32_16x16x32_bf16(af[mf], bg[nf], accG[mf][nf], 0, 0, 0);
          accU[mf][nf] = __builtin_amdgcn_mfma_f32_16x16x32_bf16(af[mf], bu[nf], accU[mf][nf], 0, 0, 0);
        }
    }
    __syncthreads();
  }

#pragma unroll
  for (int mf = 0; mf < 4; ++mf)
#pragma unroll
    for (int nf = 0; nf < 2; ++nf) {
      const int col = n_base + wave_n + nf * 16 + l16;
#pragma unroll
      for (int j = 0; j < 4; ++j) {
        const int r = m_base + wave_m + mf * 16 + quad * 4 + j;
        if (r < n_e) {
          const float g = accG[mf][nf][j];
          const float u = accU[mf][nf][j];
          const float a = (g / (1.f + __expf(-g))) * u;
          Abuf[(size_t)(off_e + r) * II + col] = f2bf(a);
        }
      }
    }
}

// ---------------- GEMM2: Y = A Wd^T; 128x64 tile; k-split x2; scatter ----------------
__global__ __launch_bounds__(256, 4)
void gemm2_kernel(const unsigned short* __restrict__ Abuf,
                  const unsigned short* __restrict__ wdt,   // [E][H][I] bf16
                  const float* __restrict__ b_down,         // [E][H] fp32
                  const int* __restrict__ offsets,
                  const int* __restrict__ mdesc,
                  const int* __restrict__ token_list,
                  const float* __restrict__ gw_list,
                  float* __restrict__ out) {
  if ((int)blockIdx.y >= mdesc[0]) return;
  const int d = mdesc[1 + blockIdx.y];
  const int e = d >> 20;
  const int m_base = d & 0xFFFFF;
  const int off_e = offsets[e];
  const int n_e = offsets[e + 1] - off_e;
  const int n_base = blockIdx.x * 64;   // H dimension
  const int split = blockIdx.z;
  const int kt_lo = split * HALF2;
  const int kt_hi = kt_lo + HALF2;

  __shared__ __attribute__((aligned(16))) unsigned short ldsA[128 * 64];
  __shared__ __attribute__((aligned(16))) unsigned short ldsB[64 * 64];

  const int tid = threadIdx.x;
  const int wave = tid >> 6;
  const int lane = tid & 63;
  const int quad = lane >> 4;
  const int l16 = lane & 15;
  const int wave_m = (wave & 1) * 64;
  const int wave_n = (wave >> 1) * 32;

  const int srow = lane >> 3;
  const int clog = (lane & 7) ^ srow;

  const unsigned short* gA[4];
  const unsigned short* gB[2];
#pragma unroll
  for (int it = 0; it < 4; ++it) {
    const int r = it * 32 + wave * 8 + srow;
    int ar = m_base + r; if (ar > n_e - 1) ar = n_e - 1;
    gA[it] = Abuf + (size_t)(off_e + ar) * II + clog * 8;
  }
#pragma unroll
  for (int it = 0; it < 2; ++it) {
    const int r = it * 32 + wave * 8 + srow;
    gB[it] = wdt + ((size_t)e * HH + (n_base + r)) * II + clog * 8;
  }

  floatx4 acc[4][2];
  const floatx4 fz = {0.f, 0.f, 0.f, 0.f};
#pragma unroll
  for (int i = 0; i < 4; ++i)
#pragma unroll
    for (int j = 0; j < 2; ++j) acc[i][j] = fz;

  for (int kt = kt_lo; kt < kt_hi; ++kt) {
    const int k0 = kt * 64;
#pragma unroll
    for (int it = 0; it < 4; ++it)
      load_lds16(gA[it] + k0, &ldsA[(it * 32 + wave * 8) * 64]);
#pragma unroll
    for (int it = 0; it < 2; ++it)
      load_lds16(gB[it] + k0, &ldsB[(it * 32 + wave * 8) * 64]);
    __syncthreads();
#pragma unroll
    for (int ks = 0; ks < 2; ++ks) {
      bf16x8 af[4], bf[2];
#pragma unroll
      for (int f = 0; f < 4; ++f) {
        const int rowA = wave_m + f * 16 + l16;
        const int cA = (ks * 4 + quad) ^ (rowA & 7);
        af[f] = *(const bf16x8*)&ldsA[rowA * 64 + cA * 8];
      }
#pragma unroll
      for (int f = 0; f < 2; ++f) {
        const int rowB = wave_n + f * 16 + l16;
        const int cB = (ks * 4 + quad) ^ (rowB & 7);
        bf[f] = *(const bf16x8*)&ldsB[rowB * 64 + cB * 8];
      }
#pragma unroll
      for (int mf = 0; mf < 4; ++mf)
#pragma unroll
        for (int nf = 0; nf < 2; ++nf)
          acc[mf][nf] = __builtin_amdgcn_mfma_f32_16x16x32_bf16(af[mf], bf[nf], acc[mf][nf], 0, 0, 0);
    }
    __syncthreads();
  }

#pragma unroll
  for (int mf = 0; mf < 4; ++mf)
#pragma unroll
    for (int nf = 0; nf < 2; ++nf) {
      const int col = n_base + wave_n + nf * 16 + l16;
      const float bd = (split == 0) ? b_down[e * HH + col] : 0.f;
#pragma unroll
      for (int j = 0; j < 4; ++j) {
        const int r = m_base + wave_m + mf * 16 + quad * 4 + j;
        if (r < n_e) {
          const int cr = off_e + r;
          const int tok = token_list[cr];
          const float gw = gw_list[cr];
          atomicAdd(&out[(size_t)tok * HH + col], gw * (acc[mf][nf][j] + bd));
        }
      }
    }
}

// ---------------- launch ----------------
extern "C" void kernel_launch(void* const* d_in, const int* in_sizes, int n_in,
                              void* d_out, int out_size, void* d_ws, size_t ws_size,
                              hipStream_t stream) {
  const float* x        = (const float*)d_in[0];
  const float* w_router = (const float*)d_in[1];
  const float* w_gate   = (const float*)d_in[2];
  const float* w_up     = (const float*)d_in[3];
  const float* w_down   = (const float*)d_in[4];
  const float* b_down   = (const float*)d_in[5];
  float* out = (float*)d_out;

  char* ws = (char*)d_ws;
  unsigned short* xb   = (unsigned short*)(ws + OFF_XB);
  unsigned short* wgt  = (unsigned short*)(ws + OFF_WGT);
  unsigned short* wut  = (unsigned short*)(ws + OFF_WUT);
  unsigned short* wdt  = (unsigned short*)(ws + OFF_WDT);
  unsigned short* Abuf = (unsigned short*)(ws + OFF_ABUF);
  int*   counts  = (int*)(ws + OFF_CNT);
  int*   offsets = (int*)(ws + OFF_OFFS);
  int*   mdesc   = (int*)(ws + OFF_MDESC);
  int*   emeta   = (int*)(ws + OFF_EMETA);
  float* wmeta   = (float*)(ws + OFF_WMETA);
  int*   tlist   = (int*)(ws + OFF_TLIST);
  float* gwl     = (float*)(ws + OFF_GWL);

  prep_kernel<<<TT * HH / 4 / 256, 256, 0, stream>>>(x, xb, out, counts);
  router_kernel<<<TT, 64, 0, stream>>>(x, w_router, counts, emeta, wmeta);
  scanfill_kernel<<<1, 256, 0, stream>>>(counts, emeta, wmeta, offsets, mdesc, tlist, gwl);
  transpose_cast_kernel<<<dim3(II / 64, HH / 64, 3 * EE), 256, 0, stream>>>(
      w_gate, w_up, w_down, wgt, wut, wdt);
  gemm1_kernel<<<dim3(II / 64, MAXTILES), 256, 0, stream>>>(xb, wgt, wut, offsets, mdesc, tlist, Abuf);
  gemm2_kernel<<<dim3(HH / 64, MAXTILES, KS2), 256, 0, stream>>>(Abuf, wdt, b_down, offsets, mdesc, tlist, gwl, out);
}